// Round 1
// 785.407 us; speedup vs baseline: 1.1237x; 1.1237x over previous
//
#include <hip/hip_runtime.h>

#define NB 32
#define NC 128
#define NH 128
#define NW 128
#define SH 64
#define SW 64
#define FLAT (NC*SH*SW)   // 524288

__device__ __forceinline__ float2 cmul(float2 a, float2 b) {
    return make_float2(a.x*b.x - a.y*b.y, a.x*b.y + a.y*b.x);
}

// ---------------- K0: init q_in accumulators with bias ----------------
__global__ void k0_init_qin(const float* __restrict__ q_in_b, float* __restrict__ qin) {
    int idx = blockIdx.x*256 + threadIdx.x;
    if (idx < 1024) {
        int k = idx >> 8, q = idx & 7;
        qin[idx] = q_in_b[k*8 + q];
    }
}

// ---------------- K1: q_in[k][b][q] += DWT(x) . W_in -----------------
// grid (128 c, 4 bg, 2 ic), block 256 = 4 waves.
// wave -> 2 batches (b0, b0+1); lane: lr = lane>>4 (row-in-group), lj = (lane&15)*4 (col quad)
// Each iter covers 4 i-rows x 64 j cols = 256 fo positions per wave.
// W loads are dwordx4 (4 consecutive fo), fully coalesced, shared across the 2 batches.
__global__ __launch_bounds__(256, 2) void k1_qin(const float* __restrict__ x,
                                                 const float* __restrict__ qw,
                                                 float* __restrict__ qin) {
    int c    = blockIdx.x;        // 0..127
    int bg   = blockIdx.y;        // 0..3
    int ic   = blockIdx.z;        // 0..1
    int wave = threadIdx.x >> 6;  // 0..3
    int lane = threadIdx.x & 63;
    int b0   = bg*8 + wave*2;     // this wave handles b0, b0+1
    int lr   = lane >> 4;         // 0..3
    int lj   = (lane & 15) << 2;  // 0,4,..,60

    const float* xb0 = x + (size_t)(b0*NC + c) * (NH*NW);
    const float* xb1 = xb0 + (size_t)NC*NH*NW;
    const float* Wb  = qw + (size_t)c * (SH*SW);

    float acc0[32], acc1[32];
    #pragma unroll
    for (int t = 0; t < 32; t++) { acc0[t] = 0.f; acc1[t] = 0.f; }

    #pragma unroll 1
    for (int it = 0; it < 8; it++) {
        int i    = ic*32 + it*4 + lr;        // 0..63
        int xoff = (2*i)*NW + 2*lj;

        float4 t00 = *(const float4*)(xb0 + xoff);
        float4 t01 = *(const float4*)(xb0 + xoff + 4);
        float4 t10 = *(const float4*)(xb0 + xoff + NW);
        float4 t11 = *(const float4*)(xb0 + xoff + NW + 4);
        float4 u00 = *(const float4*)(xb1 + xoff);
        float4 u01 = *(const float4*)(xb1 + xoff + 4);
        float4 u10 = *(const float4*)(xb1 + xoff + NW);
        float4 u11 = *(const float4*)(xb1 + xoff + NW + 4);

        // s[k][jj]: unscaled DWT combos (0.5 folded into epilogue)
        float s0[4][4], s1[4][4];
        {
            // batch b0
            float tp, tm, bp, bm;
            tp = t00.x + t00.y; tm = t00.x - t00.y; bp = t10.x + t10.y; bm = t10.x - t10.y;
            s0[0][0] = tp + bp; s0[1][0] = tp - bp; s0[2][0] = tm + bm; s0[3][0] = tm - bm;
            tp = t00.z + t00.w; tm = t00.z - t00.w; bp = t10.z + t10.w; bm = t10.z - t10.w;
            s0[0][1] = tp + bp; s0[1][1] = tp - bp; s0[2][1] = tm + bm; s0[3][1] = tm - bm;
            tp = t01.x + t01.y; tm = t01.x - t01.y; bp = t11.x + t11.y; bm = t11.x - t11.y;
            s0[0][2] = tp + bp; s0[1][2] = tp - bp; s0[2][2] = tm + bm; s0[3][2] = tm - bm;
            tp = t01.z + t01.w; tm = t01.z - t01.w; bp = t11.z + t11.w; bm = t11.z - t11.w;
            s0[0][3] = tp + bp; s0[1][3] = tp - bp; s0[2][3] = tm + bm; s0[3][3] = tm - bm;
            // batch b0+1
            tp = u00.x + u00.y; tm = u00.x - u00.y; bp = u10.x + u10.y; bm = u10.x - u10.y;
            s1[0][0] = tp + bp; s1[1][0] = tp - bp; s1[2][0] = tm + bm; s1[3][0] = tm - bm;
            tp = u00.z + u00.w; tm = u00.z - u00.w; bp = u10.z + u10.w; bm = u10.z - u10.w;
            s1[0][1] = tp + bp; s1[1][1] = tp - bp; s1[2][1] = tm + bm; s1[3][1] = tm - bm;
            tp = u01.x + u01.y; tm = u01.x - u01.y; bp = u11.x + u11.y; bm = u11.x - u11.y;
            s1[0][2] = tp + bp; s1[1][2] = tp - bp; s1[2][2] = tm + bm; s1[3][2] = tm - bm;
            tp = u01.z + u01.w; tm = u01.z - u01.w; bp = u11.z + u11.w; bm = u11.z - u11.w;
            s1[0][3] = tp + bp; s1[1][3] = tp - bp; s1[2][3] = tm + bm; s1[3][3] = tm - bm;
        }

        const float* wp = Wb + (size_t)(i*64 + lj);
        #pragma unroll
        for (int kq = 0; kq < 32; kq++) {
            float4 w = *(const float4*)(wp + (size_t)kq*FLAT);
            int k = kq >> 3;
            acc0[kq] += s0[k][0]*w.x + s0[k][1]*w.y + s0[k][2]*w.z + s0[k][3]*w.w;
            acc1[kq] += s1[k][0]*w.x + s1[k][1]*w.y + s1[k][2]*w.z + s1[k][3]*w.w;
        }
    }

    // full butterfly reduce; lane t keeps acc0[t], lane t+32 keeps acc1[t];
    // single wave-wide atomic at the end (64 lanes -> 64 distinct addresses)
    float myv = 0.f;
    #pragma unroll
    for (int t = 0; t < 32; t++) {
        float v0 = acc0[t], v1 = acc1[t];
        #pragma unroll
        for (int off = 32; off >= 1; off >>= 1) {
            v0 += __shfl_xor(v0, off, 64);
            v1 += __shfl_xor(v1, off, 64);
        }
        if (lane == t)      myv = v0;
        if (lane == t + 32) myv = v1;
    }
    int t  = lane & 31;
    int bb = b0 + (lane >> 5);
    atomicAdd(&qin[(t>>3)*256 + bb*8 + (t&7)], 0.5f*myv);
}

// ---------------- K2: 8-qubit state-vector sim, 1 block per (k,b) ----
__global__ __launch_bounds__(256) void k2_qsim(const float* __restrict__ qin,
                                               const float* __restrict__ qweights,
                                               float* __restrict__ ev) {
    int k = blockIdx.x >> 5, b = blockIdx.x & 31;
    int tid = threadIdx.x;
    __shared__ float2 st[256];
    __shared__ float  pr[256];
    __shared__ float  ang[8];
    if (tid < 8) ang[tid] = qin[(k*32+b)*8 + tid];
    st[tid] = make_float2(tid == 0 ? 1.f : 0.f, 0.f);
    __syncthreads();
    // RX(angle_q) on qubit q  (bit position 7-q, axis order MSB-first)
    for (int q = 0; q < 8; q++) {
        int bp = 7-q;
        float h = 0.5f*ang[q];
        float cA = cosf(h), sA = sinf(h);
        float2 self = st[tid];
        float2 part = st[tid ^ (1<<bp)];
        float2 nv = make_float2(cA*self.x + sA*part.y, cA*self.y - sA*part.x);
        __syncthreads(); st[tid] = nv; __syncthreads();
    }
    for (int l = 0; l < 3; l++) {
        for (int q = 0; q < 8; q++) {
            const float* w = qweights + ((k*3 + l)*8 + q)*3;
            float phi = w[0], th = w[1], om = w[2];
            float ct = cosf(0.5f*th), sst = sinf(0.5f*th);
            float ap = -0.5f*(phi+om), am = -0.5f*(phi-om);
            float cp = cosf(ap), sp = sinf(ap), cm = cosf(am), sm = sinf(am);
            float2 U00 = make_float2( cp*ct,  sp*ct);
            float2 U01 = make_float2(-cm*sst, sm*sst);
            float2 U10 = make_float2( cm*sst, sm*sst);
            float2 U11 = make_float2( cp*ct, -sp*ct);
            int bp = 7-q;
            int bit = (tid>>bp)&1;
            float2 self = st[tid], part = st[tid ^ (1<<bp)];
            float2 m0, m1;
            if (bit == 0) { m0 = cmul(U00, self); m1 = cmul(U01, part); }
            else          { m0 = cmul(U10, part); m1 = cmul(U11, self); }
            float2 nv = make_float2(m0.x + m1.x, m0.y + m1.y);
            __syncthreads(); st[tid] = nv; __syncthreads();
        }
        // CNOT chain (q -> q+1), then (7 -> 0)
        for (int q = 0; q < 7; q++) {
            int bc = 7-q, bt = 6-q;
            float2 v = ((tid>>bc)&1) ? st[tid ^ (1<<bt)] : st[tid];
            __syncthreads(); st[tid] = v; __syncthreads();
        }
        {
            int bc = 0, bt = 7;
            float2 v = ((tid>>bc)&1) ? st[tid ^ (1<<bt)] : st[tid];
            __syncthreads(); st[tid] = v; __syncthreads();
        }
    }
    pr[tid] = st[tid].x*st[tid].x + st[tid].y*st[tid].y;
    __syncthreads();
    if (tid < 8) {
        int bp = 7 - tid;
        float s = 0.f;
        for (int i = 0; i < 256; i++) s += ((i>>bp)&1) ? -pr[i] : pr[i];
        ev[(k*32+b)*8 + tid] = s;
    }
}

// ---------------- K3: G = fuse_W @ q_out_W (and Gb = fuse_W @ q_out_b)
// per k: (128o x 128c) @ (128c x 36864n); tile 128x128, micro 8x8
__global__ __launch_bounds__(256) void k3_gemmG(const float* __restrict__ q_out_W,
                                                const float* __restrict__ q_out_b,
                                                const float* __restrict__ fuse_W,
                                                float* __restrict__ Gb,
                                                float* __restrict__ G) {
    int k = blockIdx.x / 288;
    int r = blockIdx.x % 288;
    const float* Bg; float* Og; int ldB; int n0;
    if (r < 256) { n0 = r*128;       Bg = q_out_W + (size_t)k*4194304; ldB = 32768; Og = G  + (size_t)k*4194304; }
    else         { n0 = (r-256)*128; Bg = q_out_b + (size_t)k*FLAT;    ldB = 4096;  Og = Gb + (size_t)k*FLAT; }
    __shared__ float As[32*132];  // As[cc][o]  (A^T, padded)
    __shared__ float Bs[32*132];  // Bs[cc][n]
    int tid = threadIdx.x;
    int ty = tid >> 4, tx = tid & 15;
    float acc[8][8];
    #pragma unroll
    for (int m = 0; m < 8; m++)
        #pragma unroll
        for (int n = 0; n < 8; n++) acc[m][n] = 0.f;
    for (int c0 = 0; c0 < 128; c0 += 32) {
        for (int idx = tid; idx < 32*128; idx += 256) {
            int o = idx >> 5, cc = idx & 31;
            As[cc*132 + o] = fuse_W[o*128 + c0 + cc];
        }
        for (int idx = tid; idx < 32*128; idx += 256) {
            int cc = idx >> 7, n = idx & 127;
            Bs[cc*132 + n] = Bg[(size_t)(c0+cc)*ldB + n0 + n];
        }
        __syncthreads();
        #pragma unroll 2
        for (int cc = 0; cc < 32; cc++) {
            float4 a0 = *(const float4*)&As[cc*132 + ty*8];
            float4 a1 = *(const float4*)&As[cc*132 + ty*8 + 4];
            float4 b0 = *(const float4*)&Bs[cc*132 + tx*8];
            float4 b1 = *(const float4*)&Bs[cc*132 + tx*8 + 4];
            float av[8] = {a0.x,a0.y,a0.z,a0.w,a1.x,a1.y,a1.z,a1.w};
            float bv[8] = {b0.x,b0.y,b0.z,b0.w,b1.x,b1.y,b1.z,b1.w};
            #pragma unroll
            for (int m = 0; m < 8; m++)
                #pragma unroll
                for (int n = 0; n < 8; n++) acc[m][n] += av[m]*bv[n];
        }
        __syncthreads();
    }
    #pragma unroll
    for (int mm = 0; mm < 8; mm++) {
        int m = ty*8 + mm;
        float* orow = Og + (size_t)m*ldB + n0 + tx*8;
        *(float4*)orow       = make_float4(acc[mm][0], acc[mm][1], acc[mm][2], acc[mm][3]);
        *(float4*)(orow + 4) = make_float4(acc[mm][4], acc[mm][5], acc[mm][6], acc[mm][7]);
    }
}

// ---------------- K4: epilogue out = x + fuse_b + IDWT(ev . G + Gb) --
// grid (64 i, 128 o), block 256 = 4 waves; lane -> j, wave -> 8 b's
__global__ __launch_bounds__(256) void k4_epilogue(const float* __restrict__ x,
                                                   const float* __restrict__ ev,
                                                   const float* __restrict__ Gb,
                                                   const float* __restrict__ G,
                                                   const float* __restrict__ fuse_b,
                                                   float* __restrict__ out) {
    int i    = blockIdx.x;          // 0..63
    int o    = blockIdx.y;          // 0..127
    int lane = threadIdx.x & 63;    // j
    int wg   = threadIdx.x >> 6;
    float4 g[4][2]; float gb[4];
    #pragma unroll
    for (int k = 0; k < 4; k++) {
        const float* gp = G + ((size_t)((k*128+o)*4096) + i*64 + lane)*8;
        g[k][0] = *(const float4*)gp;
        g[k][1] = *(const float4*)(gp + 4);
        gb[k]   = Gb[(size_t)(k*128+o)*4096 + i*64 + lane];
    }
    float fb = fuse_b[o];
    for (int bi = 0; bi < 8; bi++) {
        int b = wg*8 + bi;
        float T[4];
        #pragma unroll
        for (int k = 0; k < 4; k++) {
            const float* e = ev + (k*32+b)*8;
            float4 e0 = *(const float4*)e;
            float4 e1 = *(const float4*)(e + 4);
            T[k] = gb[k]
                 + e0.x*g[k][0].x + e0.y*g[k][0].y + e0.z*g[k][0].z + e0.w*g[k][0].w
                 + e1.x*g[k][1].x + e1.y*g[k][1].y + e1.z*g[k][1].z + e1.w*g[k][1].w;
        }
        float pa = 0.5f*(T[0]+T[1]+T[2]+T[3]) + fb;
        float pb = 0.5f*(T[0]+T[1]-T[2]-T[3]) + fb;
        float pc = 0.5f*(T[0]-T[1]+T[2]-T[3]) + fb;
        float pd = 0.5f*(T[0]-T[1]-T[2]+T[3]) + fb;
        size_t base = ((size_t)(b*128 + o)*128 + 2*i)*128 + 2*lane;
        float2 x0 = *(const float2*)(x + base);
        float2 x1 = *(const float2*)(x + base + 128);
        *(float2*)(out + base)       = make_float2(x0.x + pa, x0.y + pb);
        *(float2*)(out + base + 128) = make_float2(x1.x + pc, x1.y + pd);
    }
}

extern "C" void kernel_launch(void* const* d_in, const int* in_sizes, int n_in,
                              void* d_out, int out_size, void* d_ws, size_t ws_size,
                              hipStream_t stream) {
    const float* x         = (const float*)d_in[0];
    const float* q_in_W    = (const float*)d_in[1];
    const float* q_in_b    = (const float*)d_in[2];
    const float* q_weights = (const float*)d_in[3];
    const float* q_out_W   = (const float*)d_in[4];
    const float* q_out_b   = (const float*)d_in[5];
    const float* fuse_W    = (const float*)d_in[6];
    const float* fuse_b    = (const float*)d_in[7];
    float* out = (float*)d_out;

    float* wsf = (float*)d_ws;
    float* qin = wsf;                         // 1024 floats  [k][b][q]
    float* ev  = wsf + 1024;                  // 1024 floats  [k][b][q]
    float* Gb  = wsf + 2048;                  // 4*128*4096   [k][o][p]
    float* G   = wsf + 2048 + 4*128*4096;     // 4*128*4096*8 [k][o][p][q]

    k0_init_qin<<<4, 256, 0, stream>>>(q_in_b, qin);
    k1_qin<<<dim3(128, 4, 2), 256, 0, stream>>>(x, q_in_W, qin);
    k2_qsim<<<128, 256, 0, stream>>>(qin, q_weights, ev);
    k3_gemmG<<<1152, 256, 0, stream>>>(q_out_W, q_out_b, fuse_W, Gb, G);
    k4_epilogue<<<dim3(64, 128), 256, 0, stream>>>(x, ev, Gb, G, fuse_b, out);
}

// Round 2
// 744.812 us; speedup vs baseline: 1.1849x; 1.0545x over previous
//
#include <hip/hip_runtime.h>

#define NB 32
#define NC 128
#define NH 128
#define NW 128
#define SH 64
#define SW 64
#define FLAT (NC*SH*SW)   // 524288

__device__ __forceinline__ float2 cmul(float2 a, float2 b) {
    return make_float2(a.x*b.x - a.y*b.y, a.x*b.y + a.y*b.x);
}

// ---------------- K0: init q_in accumulators with bias ----------------
__global__ void k0_init_qin(const float* __restrict__ q_in_b, float* __restrict__ qin) {
    int idx = blockIdx.x*256 + threadIdx.x;
    if (idx < 1024) {
        int k = idx >> 8, q = idx & 7;
        qin[idx] = q_in_b[k*8 + q];
    }
}

// ---------------- K1: q_in[k][b][q] += DWT(x) . W_in -----------------
// grid (128 c, 4 bg, 2 ic), block 256 = 4 waves.
// wave -> 2 batches (b0, b0+1); lane: lr = lane>>4 (row-in-group), lj = (lane&15)*4 (col quad)
__global__ __launch_bounds__(256, 2) void k1_qin(const float* __restrict__ x,
                                                 const float* __restrict__ qw,
                                                 float* __restrict__ qin) {
    int c    = blockIdx.x;        // 0..127
    int bg   = blockIdx.y;        // 0..3
    int ic   = blockIdx.z;        // 0..1
    int wave = threadIdx.x >> 6;  // 0..3
    int lane = threadIdx.x & 63;
    int b0   = bg*8 + wave*2;     // this wave handles b0, b0+1
    int lr   = lane >> 4;         // 0..3
    int lj   = (lane & 15) << 2;  // 0,4,..,60

    const float* xb0 = x + (size_t)(b0*NC + c) * (NH*NW);
    const float* xb1 = xb0 + (size_t)NC*NH*NW;
    const float* Wb  = qw + (size_t)c * (SH*SW);

    float acc0[32], acc1[32];
    #pragma unroll
    for (int t = 0; t < 32; t++) { acc0[t] = 0.f; acc1[t] = 0.f; }

    #pragma unroll 1
    for (int it = 0; it < 8; it++) {
        int i    = ic*32 + it*4 + lr;        // 0..63
        int xoff = (2*i)*NW + 2*lj;

        float4 t00 = *(const float4*)(xb0 + xoff);
        float4 t01 = *(const float4*)(xb0 + xoff + 4);
        float4 t10 = *(const float4*)(xb0 + xoff + NW);
        float4 t11 = *(const float4*)(xb0 + xoff + NW + 4);
        float4 u00 = *(const float4*)(xb1 + xoff);
        float4 u01 = *(const float4*)(xb1 + xoff + 4);
        float4 u10 = *(const float4*)(xb1 + xoff + NW);
        float4 u11 = *(const float4*)(xb1 + xoff + NW + 4);

        // s[k][jj]: unscaled DWT combos (0.5 folded into epilogue)
        float s0[4][4], s1[4][4];
        {
            float tp, tm, bp, bm;
            tp = t00.x + t00.y; tm = t00.x - t00.y; bp = t10.x + t10.y; bm = t10.x - t10.y;
            s0[0][0] = tp + bp; s0[1][0] = tp - bp; s0[2][0] = tm + bm; s0[3][0] = tm - bm;
            tp = t00.z + t00.w; tm = t00.z - t00.w; bp = t10.z + t10.w; bm = t10.z - t10.w;
            s0[0][1] = tp + bp; s0[1][1] = tp - bp; s0[2][1] = tm + bm; s0[3][1] = tm - bm;
            tp = t01.x + t01.y; tm = t01.x - t01.y; bp = t11.x + t11.y; bm = t11.x - t11.y;
            s0[0][2] = tp + bp; s0[1][2] = tp - bp; s0[2][2] = tm + bm; s0[3][2] = tm - bm;
            tp = t01.z + t01.w; tm = t01.z - t01.w; bp = t11.z + t11.w; bm = t11.z - t11.w;
            s0[0][3] = tp + bp; s0[1][3] = tp - bp; s0[2][3] = tm + bm; s0[3][3] = tm - bm;
            tp = u00.x + u00.y; tm = u00.x - u00.y; bp = u10.x + u10.y; bm = u10.x - u10.y;
            s1[0][0] = tp + bp; s1[1][0] = tp - bp; s1[2][0] = tm + bm; s1[3][0] = tm - bm;
            tp = u00.z + u00.w; tm = u00.z - u00.w; bp = u10.z + u10.w; bm = u10.z - u10.w;
            s1[0][1] = tp + bp; s1[1][1] = tp - bp; s1[2][1] = tm + bm; s1[3][1] = tm - bm;
            tp = u01.x + u01.y; tm = u01.x - u01.y; bp = u11.x + u11.y; bm = u11.x - u11.y;
            s1[0][2] = tp + bp; s1[1][2] = tp - bp; s1[2][2] = tm + bm; s1[3][2] = tm - bm;
            tp = u01.z + u01.w; tm = u01.z - u01.w; bp = u11.z + u11.w; bm = u11.z - u11.w;
            s1[0][3] = tp + bp; s1[1][3] = tp - bp; s1[2][3] = tm + bm; s1[3][3] = tm - bm;
        }

        const float* wp = Wb + (size_t)(i*64 + lj);
        #pragma unroll
        for (int kq = 0; kq < 32; kq++) {
            float4 w = *(const float4*)(wp + (size_t)kq*FLAT);
            int k = kq >> 3;
            acc0[kq] += s0[k][0]*w.x + s0[k][1]*w.y + s0[k][2]*w.z + s0[k][3]*w.w;
            acc1[kq] += s1[k][0]*w.x + s1[k][1]*w.y + s1[k][2]*w.z + s1[k][3]*w.w;
        }
    }

    float myv = 0.f;
    #pragma unroll
    for (int t = 0; t < 32; t++) {
        float v0 = acc0[t], v1 = acc1[t];
        #pragma unroll
        for (int off = 32; off >= 1; off >>= 1) {
            v0 += __shfl_xor(v0, off, 64);
            v1 += __shfl_xor(v1, off, 64);
        }
        if (lane == t)      myv = v0;
        if (lane == t + 32) myv = v1;
    }
    int t  = lane & 31;
    int bb = b0 + (lane >> 5);
    atomicAdd(&qin[(t>>3)*256 + bb*8 + (t&7)], 0.5f*myv);
}

// ---------------- K2: 8-qubit state-vector sim, 1 block per (k,b) ----
__global__ __launch_bounds__(256) void k2_qsim(const float* __restrict__ qin,
                                               const float* __restrict__ qweights,
                                               float* __restrict__ ev) {
    int k = blockIdx.x >> 5, b = blockIdx.x & 31;
    int tid = threadIdx.x;
    __shared__ float2 st[256];
    __shared__ float  pr[256];
    __shared__ float  ang[8];
    if (tid < 8) ang[tid] = qin[(k*32+b)*8 + tid];
    st[tid] = make_float2(tid == 0 ? 1.f : 0.f, 0.f);
    __syncthreads();
    for (int q = 0; q < 8; q++) {
        int bp = 7-q;
        float h = 0.5f*ang[q];
        float cA = cosf(h), sA = sinf(h);
        float2 self = st[tid];
        float2 part = st[tid ^ (1<<bp)];
        float2 nv = make_float2(cA*self.x + sA*part.y, cA*self.y - sA*part.x);
        __syncthreads(); st[tid] = nv; __syncthreads();
    }
    for (int l = 0; l < 3; l++) {
        for (int q = 0; q < 8; q++) {
            const float* w = qweights + ((k*3 + l)*8 + q)*3;
            float phi = w[0], th = w[1], om = w[2];
            float ct = cosf(0.5f*th), sst = sinf(0.5f*th);
            float ap = -0.5f*(phi+om), am = -0.5f*(phi-om);
            float cp = cosf(ap), sp = sinf(ap), cm = cosf(am), sm = sinf(am);
            float2 U00 = make_float2( cp*ct,  sp*ct);
            float2 U01 = make_float2(-cm*sst, sm*sst);
            float2 U10 = make_float2( cm*sst, sm*sst);
            float2 U11 = make_float2( cp*ct, -sp*ct);
            int bp = 7-q;
            int bit = (tid>>bp)&1;
            float2 self = st[tid], part = st[tid ^ (1<<bp)];
            float2 m0, m1;
            if (bit == 0) { m0 = cmul(U00, self); m1 = cmul(U01, part); }
            else          { m0 = cmul(U10, part); m1 = cmul(U11, self); }
            float2 nv = make_float2(m0.x + m1.x, m0.y + m1.y);
            __syncthreads(); st[tid] = nv; __syncthreads();
        }
        for (int q = 0; q < 7; q++) {
            int bc = 7-q, bt = 6-q;
            float2 v = ((tid>>bc)&1) ? st[tid ^ (1<<bt)] : st[tid];
            __syncthreads(); st[tid] = v; __syncthreads();
        }
        {
            int bc = 0, bt = 7;
            float2 v = ((tid>>bc)&1) ? st[tid ^ (1<<bt)] : st[tid];
            __syncthreads(); st[tid] = v; __syncthreads();
        }
    }
    pr[tid] = st[tid].x*st[tid].x + st[tid].y*st[tid].y;
    __syncthreads();
    if (tid < 8) {
        int bp = 7 - tid;
        float s = 0.f;
        for (int i = 0; i < 256; i++) s += ((i>>bp)&1) ? -pr[i] : pr[i];
        ev[(k*32+b)*8 + tid] = s;
    }
}

// ---------------- K3: G = fuse_W @ q_out_W (and Gb = fuse_W @ q_out_b)
__global__ __launch_bounds__(256) void k3_gemmG(const float* __restrict__ q_out_W,
                                                const float* __restrict__ q_out_b,
                                                const float* __restrict__ fuse_W,
                                                float* __restrict__ Gb,
                                                float* __restrict__ G) {
    int k = blockIdx.x / 288;
    int r = blockIdx.x % 288;
    const float* Bg; float* Og; int ldB; int n0;
    if (r < 256) { n0 = r*128;       Bg = q_out_W + (size_t)k*4194304; ldB = 32768; Og = G  + (size_t)k*4194304; }
    else         { n0 = (r-256)*128; Bg = q_out_b + (size_t)k*FLAT;    ldB = 4096;  Og = Gb + (size_t)k*FLAT; }
    __shared__ float As[32*132];  // As[cc][o]  (A^T, padded)
    __shared__ float Bs[32*132];  // Bs[cc][n]
    int tid = threadIdx.x;
    int ty = tid >> 4, tx = tid & 15;
    float acc[8][8];
    #pragma unroll
    for (int m = 0; m < 8; m++)
        #pragma unroll
        for (int n = 0; n < 8; n++) acc[m][n] = 0.f;
    for (int c0 = 0; c0 < 128; c0 += 32) {
        for (int idx = tid; idx < 32*128; idx += 256) {
            int o = idx >> 5, cc = idx & 31;
            As[cc*132 + o] = fuse_W[o*128 + c0 + cc];
        }
        for (int idx = tid; idx < 32*128; idx += 256) {
            int cc = idx >> 7, n = idx & 127;
            Bs[cc*132 + n] = Bg[(size_t)(c0+cc)*ldB + n0 + n];
        }
        __syncthreads();
        #pragma unroll 2
        for (int cc = 0; cc < 32; cc++) {
            float4 a0 = *(const float4*)&As[cc*132 + ty*8];
            float4 a1 = *(const float4*)&As[cc*132 + ty*8 + 4];
            float4 b0 = *(const float4*)&Bs[cc*132 + tx*8];
            float4 b1 = *(const float4*)&Bs[cc*132 + tx*8 + 4];
            float av[8] = {a0.x,a0.y,a0.z,a0.w,a1.x,a1.y,a1.z,a1.w};
            float bv[8] = {b0.x,b0.y,b0.z,b0.w,b1.x,b1.y,b1.z,b1.w};
            #pragma unroll
            for (int m = 0; m < 8; m++)
                #pragma unroll
                for (int n = 0; n < 8; n++) acc[m][n] += av[m]*bv[n];
        }
        __syncthreads();
    }
    #pragma unroll
    for (int mm = 0; mm < 8; mm++) {
        int m = ty*8 + mm;
        float* orow = Og + (size_t)m*ldB + n0 + tx*8;
        *(float4*)orow       = make_float4(acc[mm][0], acc[mm][1], acc[mm][2], acc[mm][3]);
        *(float4*)(orow + 4) = make_float4(acc[mm][4], acc[mm][5], acc[mm][6], acc[mm][7]);
    }
}

// ---------------- K4: epilogue out = x + fuse_b + IDWT(ev . G + Gb) --
// grid (64 i, 128 o), block 256 = 4 waves.
// lane: half = lane>>5 picks row 2i / 2i+1; lo = lane&31 picks 4-wide w-quad.
// Each lane: float4 x-load / out-store (1 KiB per wave-instruction), handles
// j0=2lo, j1=2lo+1. G coeffs (64 f/lane) hoisted, reused over all 32 batches.
// ev staged in LDS (broadcast ds_reads). Branch-free IDWT select via `half`.
__global__ __launch_bounds__(256, 4) void k4_epilogue(const float* __restrict__ x,
                                                      const float* __restrict__ ev,
                                                      const float* __restrict__ Gb,
                                                      const float* __restrict__ G,
                                                      const float* __restrict__ fuse_b,
                                                      float* __restrict__ out) {
    int i    = blockIdx.x;          // 0..63
    int o    = blockIdx.y;          // 0..127
    int tid  = threadIdx.x;
    int wg   = tid >> 6;            // wave -> 8 b's
    int lane = tid & 63;
    int half = lane >> 5;           // 0: row 2i, 1: row 2i+1
    int lo   = lane & 31;           // w-quad

    __shared__ float evs[1024];
    *(float4*)(evs + tid*4) = *(const float4*)(ev + tid*4);

    // G coefficients for j0=2lo (g[k][0..1]) and j1=2lo+1 (g[k][2..3])
    float4 g[4][4];
    float  gb2[4][2];
    #pragma unroll
    for (int k = 0; k < 4; k++) {
        const float* gp = G + ((size_t)((k*128+o)*4096) + i*64 + 2*lo)*8;
        g[k][0] = *(const float4*)(gp);
        g[k][1] = *(const float4*)(gp + 4);
        g[k][2] = *(const float4*)(gp + 8);
        g[k][3] = *(const float4*)(gp + 12);
        const float* gbp = Gb + (size_t)(k*128+o)*4096 + i*64 + 2*lo;
        gb2[k][0] = gbp[0];
        gb2[k][1] = gbp[1];
    }
    float fb = fuse_b[o];
    __syncthreads();

    #pragma unroll 2
    for (int bi = 0; bi < 8; bi++) {
        int b = wg*8 + bi;
        size_t base = ((size_t)(b*128 + o)*128 + 2*i + half)*128 + 4*lo;
        float4 xv = *(const float4*)(x + base);
        float T0[4], T1[4];
        #pragma unroll
        for (int k = 0; k < 4; k++) {
            const float* e = evs + (k*32+b)*8;
            float4 e0 = *(const float4*)e;
            float4 e1 = *(const float4*)(e + 4);
            T0[k] = gb2[k][0]
                  + e0.x*g[k][0].x + e0.y*g[k][0].y + e0.z*g[k][0].z + e0.w*g[k][0].w
                  + e1.x*g[k][1].x + e1.y*g[k][1].y + e1.z*g[k][1].z + e1.w*g[k][1].w;
            T1[k] = gb2[k][1]
                  + e0.x*g[k][2].x + e0.y*g[k][2].y + e0.z*g[k][2].z + e0.w*g[k][2].w
                  + e1.x*g[k][3].x + e1.y*g[k][3].y + e1.z*g[k][3].z + e1.w*g[k][3].w;
        }
        // row 2i   (half=0): w even = pa = .5(U+V), w odd = pb = .5(U-V), U=T0+T1, V=T2+T3
        // row 2i+1 (half=1): w even = pc = .5(P+Q), w odd = pd = .5(P-Q), P=T0-T1, Q=T2-T3
        float A0 = half ? (T0[0]-T0[1]) : (T0[0]+T0[1]);
        float B0 = half ? (T0[2]-T0[3]) : (T0[2]+T0[3]);
        float A1 = half ? (T1[0]-T1[1]) : (T1[0]+T1[1]);
        float B1 = half ? (T1[2]-T1[3]) : (T1[2]+T1[3]);
        float4 ov;
        ov.x = xv.x + 0.5f*(A0+B0) + fb;
        ov.y = xv.y + 0.5f*(A0-B0) + fb;
        ov.z = xv.z + 0.5f*(A1+B1) + fb;
        ov.w = xv.w + 0.5f*(A1-B1) + fb;
        *(float4*)(out + base) = ov;
    }
}

extern "C" void kernel_launch(void* const* d_in, const int* in_sizes, int n_in,
                              void* d_out, int out_size, void* d_ws, size_t ws_size,
                              hipStream_t stream) {
    const float* x         = (const float*)d_in[0];
    const float* q_in_W    = (const float*)d_in[1];
    const float* q_in_b    = (const float*)d_in[2];
    const float* q_weights = (const float*)d_in[3];
    const float* q_out_W   = (const float*)d_in[4];
    const float* q_out_b   = (const float*)d_in[5];
    const float* fuse_W    = (const float*)d_in[6];
    const float* fuse_b    = (const float*)d_in[7];
    float* out = (float*)d_out;

    float* wsf = (float*)d_ws;
    float* qin = wsf;                         // 1024 floats  [k][b][q]
    float* ev  = wsf + 1024;                  // 1024 floats  [k][b][q]
    float* Gb  = wsf + 2048;                  // 4*128*4096   [k][o][p]
    float* G   = wsf + 2048 + 4*128*4096;     // 4*128*4096*8 [k][o][p][q]

    k0_init_qin<<<4, 256, 0, stream>>>(q_in_b, qin);
    k1_qin<<<dim3(128, 4, 2), 256, 0, stream>>>(x, q_in_W, qin);
    k2_qsim<<<128, 256, 0, stream>>>(qin, q_weights, ev);
    k3_gemmG<<<1152, 256, 0, stream>>>(q_out_W, q_out_b, fuse_W, Gb, G);
    k4_epilogue<<<dim3(64, 128), 256, 0, stream>>>(x, ev, Gb, G, fuse_b, out);
}